// Round 8
// baseline (121.991 us; speedup 1.0000x reference)
//
#include <hip/hip_runtime.h>

#define D 4096
#define H 512
#define NCH 64
#define CCH 64
#define B 8

typedef __bf16 bf16x8 __attribute__((ext_vector_type(8)));
typedef float  f32x4  __attribute__((ext_vector_type(4)));

// workspace layout (float offsets)
#define OFF_P    0                         // P_nh[n][h]           32768
#define OFF_C    (OFF_P + NCH*H)           // c[h]                 512   (memset 0)
#define OFF_U    (OFF_C + H)               // u[b][h]              4096  (memset 0, atomic)
#define OFF_VN2  (OFF_U + B*H)             // ||v_b||^2            16    (memset 0, atomic)
#define OFF_A1   (OFF_VN2 + 16)            // a1[b][n*64+i]        32768
#define OFF_ZB   (OFF_A1 + B*NCH*CCH)      // zblk[b][i][n*64+k]   2097152
#define OFF_W1H  (OFF_ZB + B*64*4096)      // W1hi bf16 [d][h]
#define OFF_W1L  (OFF_W1H + (D*H)/2)       // W1lo bf16 [d][h]
#define OFF_WH   (OFF_W1L + (D*H)/2)       // whi bf16 [b][n][h]
#define OFF_WL   (OFF_WH + (B*NCH*H)/2)    // wlo bf16 [b][n][h]

__device__ __forceinline__ unsigned short bfbits(float x) {
    union { __bf16 b; unsigned short u; } cv;
    cv.b = (__bf16)x;                       // RNE via v_cvt_pk_bf16_f32
    return cv.u;
}
__device__ __forceinline__ float bfval(float x) {
    return (float)(__bf16)x;
}

// K1: 512 blocks (n-chunk, h-64-slice) x 128 thr. float4 over h, j split 8 ways.
// Produces: W1 bf16 hi/lo, P[n][h]; atomicAdds u[b][h], c[h], ||v||^2 (pre-zeroed).
__global__ __launch_bounds__(128) void k1_reduce_w1(const float* __restrict__ W1,
                                                    const float* __restrict__ state,
                                                    const float* __restrict__ x0,
                                                    const float* __restrict__ x1,
                                                    const float* __restrict__ tptr,
                                                    float* __restrict__ ws) {
    int n   = blockIdx.x;              // 0..63
    int ht  = blockIdx.y;              // 0..7 (h-slice; doubles as b for ||v||^2)
    int tid = threadIdx.x;             // 0..127
    int hq  = ht * 16 + (tid & 15);    // global float4-group of h: 0..127
    int jh  = tid >> 4;                // 0..7 (j-eighth)

    __shared__ float xs[B][64];
    __shared__ f32x4 red[8][16][9];    // [jh][lane][p,up0..up7]

    float ts = tptr[0];
    float window = 4.f * ts * (1.f - ts);
    if (tid < 64) {
        int d = n * 64 + tid;
        for (int b = 0; b < B; ++b) {
            float a0 = x0[b * D + d];
            float a1v = x1[b * D + d];
            float dev = state[b * D + d];
            xs[b][tid] = a0 + ts * (a1v - a0) + window * dev;
        }
    }
    __syncthreads();

    unsigned short* __restrict__ W1Hp = (unsigned short*)(ws + OFF_W1H);
    unsigned short* __restrict__ W1Lp = (unsigned short*)(ws + OFF_W1L);

    f32x4 p4 = {0.f, 0.f, 0.f, 0.f};
    f32x4 up[B];
#pragma unroll
    for (int b = 0; b < B; ++b) up[b] = p4;

#pragma unroll
    for (int jj = 0; jj < 8; ++jj) {
        int j = jh * 8 + jj;
        int d = n * 64 + j;
        f32x4 w = ((const f32x4*)W1)[d * (H / 4) + hq];
        p4 += w;
#pragma unroll
        for (int b = 0; b < B; ++b) up[b] += w * xs[b][j];
        ushort4 hv = {bfbits(w.x), bfbits(w.y), bfbits(w.z), bfbits(w.w)};
        ushort4 lv = {bfbits(w.x - bfval(w.x)), bfbits(w.y - bfval(w.y)),
                      bfbits(w.z - bfval(w.z)), bfbits(w.w - bfval(w.w))};
        *(ushort4*)(W1Hp + d * H + hq * 4) = hv;
        *(ushort4*)(W1Lp + d * H + hq * 4) = lv;
    }

    // ||v||^2 partial: this block covers d-chunk n for sample b = ht (wave 0)
    if (tid < 64) {
        float vv = state[(size_t)(B + ht) * D + n * 64 + tid];
        float v2 = vv * vv;
#pragma unroll
        for (int mk = 1; mk < 64; mk <<= 1) v2 += __shfl_xor(v2, mk);
        if (tid == 0) atomicAdd(&ws[OFF_VN2 + ht], v2);
    }

    int l = tid & 15;
    red[jh][l][0] = p4;
#pragma unroll
    for (int b = 0; b < B; ++b) red[jh][l][1 + b] = up[b];
    __syncthreads();

    if (tid < 16) {
        f32x4 pt = red[0][l][0];
        f32x4 ut[B];
#pragma unroll
        for (int b = 0; b < B; ++b) ut[b] = red[0][l][1 + b];
        for (int g = 1; g < 8; ++g) {
            pt += red[g][l][0];
#pragma unroll
            for (int b = 0; b < B; ++b) ut[b] += red[g][l][1 + b];
        }
        *(f32x4*)(ws + OFF_P + n * H + hq * 4) = pt;
#pragma unroll
        for (int e = 0; e < 4; ++e) atomicAdd(&ws[OFF_C + hq * 4 + e], pt[e]);
#pragma unroll
        for (int b = 0; b < B; ++b)
#pragma unroll
            for (int e = 0; e < 4; ++e)
                atomicAdd(&ws[OFF_U + b * H + hq * 4 + e], ut[b][e]);
    }
}

// K3: 512 blocks (n,b) x 64 thr. In-block: s,st2 from u; M and msum shuffle-reduce;
// r, q on the fly; w -> bf16 hi/lo.
__global__ void k3_w(const float* __restrict__ W2,
                     float* __restrict__ ws) {
    int n = blockIdx.x, b = blockIdx.y, lane = threadIdx.x;   // 64 threads
    float M[8], Q[8], s2j[8];
#pragma unroll
    for (int o = 0; o < 8; ++o) { M[o] = 0.f; Q[o] = 0.f; }

#pragma unroll
    for (int j = 0; j < 8; ++j) {
        int h = j * 64 + lane;
        float u  = ws[OFF_U + b * H + h];
        float tt = tanhf(u);
        float s  = 1.f - tt * tt;
        s2j[j]   = -2.f * tt * s;
        float c  = ws[OFF_C + h];
        float P  = ws[OFF_P + n * H + h];
        float ps = P * s, cs = c * s;
        const float4* wp = (const float4*)(W2 + h * 8);
        float4 wa = wp[0], wb = wp[1];
        M[0] += ps * wa.x; M[1] += ps * wa.y; M[2] += ps * wa.z; M[3] += ps * wa.w;
        M[4] += ps * wb.x; M[5] += ps * wb.y; M[6] += ps * wb.z; M[7] += ps * wb.w;
        Q[0] += cs * wa.x; Q[1] += cs * wa.y; Q[2] += cs * wa.z; Q[3] += cs * wa.w;
        Q[4] += cs * wb.x; Q[5] += cs * wb.y; Q[6] += cs * wb.z; Q[7] += cs * wb.w;
    }
#pragma unroll
    for (int mk = 1; mk < 64; mk <<= 1)
#pragma unroll
        for (int o = 0; o < 8; ++o) {
            M[o] += __shfl_xor(M[o], mk);
            Q[o] += __shfl_xor(Q[o], mk);
        }

    unsigned short* __restrict__ WHp = (unsigned short*)(ws + OFF_WH);
    unsigned short* __restrict__ WLp = (unsigned short*)(ws + OFF_WL);
#pragma unroll
    for (int j = 0; j < 8; ++j) {
        int h = j * 64 + lane;
        const float4* wp = (const float4*)(W2 + h * 8);
        float4 wa = wp[0], wb = wp[1];
        float r = wa.x*M[0] + wa.y*M[1] + wa.z*M[2] + wa.w*M[3]
                + wb.x*M[4] + wb.y*M[5] + wb.z*M[6] + wb.w*M[7];
        float q = wa.x*Q[0] + wa.y*Q[1] + wa.z*Q[2] + wa.w*Q[3]
                + wb.x*Q[4] + wb.y*Q[5] + wb.z*Q[6] + wb.w*Q[7];
        float P = ws[OFF_P + n * H + h];
        float c = ws[OFF_C + h];
        float wval = s2j[j] * (P * q + c * r);
        WHp[(b * NCH + n) * H + h] = bfbits(wval);
        WLp[(b * NCH + n) * H + h] = bfbits(wval - bfval(wval));
    }
}

// K4: 256 blocks x 512 thr; 2 (i,b)-units per block (shared i => shared W1 reads);
// per unit 4 waves split K; named register double-buffer; LDS cross-wave reduce;
// fused norm/y/z epilogue.
__global__ __launch_bounds__(512, 2) void k4_mfma(const float* __restrict__ state,
                                                  float* __restrict__ ws) {
    int bid  = blockIdx.x;        // 0..255
    int tid  = threadIdx.x;       // 0..511
    int g    = tid >> 8;          // unit within block
    int gt   = tid & 255;
    int u    = bid * 2 + g;
    int i    = u >> 3, b = u & 7; // both units share i
    int wvid = gt >> 6;
    int lane = tid & 63;
    int r16  = lane & 15;
    int kgrp = (lane >> 4) * 8;

    __shared__ float gp[2][2][64][67];
    __shared__ float coefs[2][64];

    const unsigned short* __restrict__ W1Hp = (const unsigned short*)(ws + OFF_W1H);
    const unsigned short* __restrict__ W1Lp = (const unsigned short*)(ws + OFF_W1L);
    const unsigned short* __restrict__ WHp  = (const unsigned short*)(ws + OFF_WH);
    const unsigned short* __restrict__ WLp  = (const unsigned short*)(ws + OFF_WL);

    f32x4 acc[4][4];
    f32x4 zz = {0.f, 0.f, 0.f, 0.f};
#pragma unroll
    for (int m = 0; m < 4; ++m)
#pragma unroll
        for (int c = 0; c < 4; ++c) acc[m][c] = zz;

    int kb    = wvid * 128 + kgrp;
    int baseA = (b * 64 + r16) * H;
    int baseB = (i * 64 + r16) * H;

    bf16x8 A0[8], B0[8], A1[8], B1[8];

#define LOADF(FA, FB, KOFS) do {                                           \
        int k_ = (KOFS);                                                   \
        _Pragma("unroll")                                                  \
        for (int m_ = 0; m_ < 4; ++m_) {                                   \
            int oA = baseA + m_ * 16 * H + k_;                             \
            FA[m_]     = *(const bf16x8*)(WHp + oA);                       \
            FA[4 + m_] = *(const bf16x8*)(WLp + oA);                       \
            int oB = baseB + m_ * 16 * H + k_;                             \
            FB[m_]     = *(const bf16x8*)(W1Hp + oB);                      \
            FB[4 + m_] = *(const bf16x8*)(W1Lp + oB);                      \
        } } while (0)

#define MFMA12(FA, FB) do {                                                \
        _Pragma("unroll")                                                  \
        for (int m = 0; m < 4; ++m)                                        \
        _Pragma("unroll")                                                  \
        for (int c = 0; c < 4; ++c) {                                      \
            acc[m][c] = __builtin_amdgcn_mfma_f32_16x16x32_bf16(FA[m], FB[c], acc[m][c], 0, 0, 0);       \
            acc[m][c] = __builtin_amdgcn_mfma_f32_16x16x32_bf16(FA[m], FB[4 + c], acc[m][c], 0, 0, 0);   \
            acc[m][c] = __builtin_amdgcn_mfma_f32_16x16x32_bf16(FA[4 + m], FB[c], acc[m][c], 0, 0, 0);   \
        } } while (0)

    LOADF(A0, B0, kb);
    LOADF(A1, B1, kb + 32);
    MFMA12(A0, B0);
    LOADF(A0, B0, kb + 64);
    MFMA12(A1, B1);
    LOADF(A1, B1, kb + 96);
    MFMA12(A0, B0);
    MFMA12(A1, B1);

#undef LOADF
#undef MFMA12

    // cross-wave K reduction within unit
    int rowb = (lane >> 4) * 4;
    if (wvid < 2) {
        float (*gpp)[67] = gp[g][wvid];
#pragma unroll
        for (int m = 0; m < 4; ++m)
#pragma unroll
            for (int c = 0; c < 4; ++c)
#pragma unroll
                for (int e = 0; e < 4; ++e)
                    gpp[m * 16 + rowb + e][c * 16 + r16] = acc[m][c][e];
    }
    __syncthreads();
    if (wvid >= 2) {
        float (*gpp)[67] = gp[g][wvid - 2];
#pragma unroll
        for (int m = 0; m < 4; ++m)
#pragma unroll
            for (int c = 0; c < 4; ++c)
#pragma unroll
                for (int e = 0; e < 4; ++e)
                    gpp[m * 16 + rowb + e][c * 16 + r16] += acc[m][c][e];
    }
    __syncthreads();

    const float* v = state + (size_t)(B + b) * D;
    if (gt < 64) {
        int n = gt;
        float ss = 0.f, y = 0.f;
#pragma unroll 8
        for (int k = 0; k < 64; ++k) {
            float gv = gp[g][0][n][k] + gp[g][1][n][k];
            ss += gv * gv;
            y  += gv * v[n * 64 + k];
        }
        float nrm = sqrtf(ss) + 1e-6f;
        ws[OFF_A1 + (size_t)(b * NCH + n) * CCH + i] = y / nrm;
        coefs[g][n] = v[n * 64 + i] / nrm;
    }
    __syncthreads();

    float* zb = ws + OFF_ZB + ((size_t)b * 64 + i) * 4096;
#pragma unroll
    for (int r = 0; r < 16; ++r) {
        int idx = gt + r * 256;
        int n = idx >> 6, k = idx & 63;
        zb[idx] = (gp[g][0][n][k] + gp[g][1][n][k]) * coefs[g][n];
    }
}

// K5: reduce z partials over i, final assembly
__global__ void k5_final(const float* __restrict__ state,
                         const float* __restrict__ ws,
                         float* __restrict__ out) {
    int idx = blockIdx.x * 512 + threadIdx.x;   // 0..32767
    float vel = state[32768 + idx];
    out[idx] = vel;
    int b = idx >> 12, e = idx & 4095;
    const float* zb = ws + OFF_ZB + (size_t)b * 64 * 4096 + e;
    float z = 0.f;
#pragma unroll 8
    for (int i = 0; i < 64; ++i) z += zb[(size_t)i * 4096];
    float a1 = ws[OFF_A1 + (size_t)b * 4096 + e];
    float vn = sqrtf(ws[OFF_VN2 + b]) + 1e-6f;
    float av = -0.5f * vel * (a1 + z) / vn;
    out[32768 + idx] = av - 0.1f * state[idx];
}

extern "C" void kernel_launch(void* const* d_in, const int* in_sizes, int n_in,
                              void* d_out, int out_size, void* d_ws, size_t ws_size,
                              hipStream_t stream) {
    const float* t   = (const float*)d_in[0];
    const float* st  = (const float*)d_in[1];
    const float* x0  = (const float*)d_in[2];
    const float* x1  = (const float*)d_in[3];
    const float* W1  = (const float*)d_in[4];
    const float* W2  = (const float*)d_in[5];
    float* out = (float*)d_out;
    float* ws  = (float*)d_ws;

    // zero the atomic accumulators: C (512) + U (4096) + VN2 (16) contiguous
    hipMemsetAsync(ws + OFF_C, 0, (H + B * H + 16) * sizeof(float), stream);
    hipLaunchKernelGGL(k1_reduce_w1, dim3(64, 8), dim3(128), 0, stream, W1, st, x0, x1, t, ws);
    hipLaunchKernelGGL(k3_w,         dim3(64, 8), dim3(64),  0, stream, W2, ws);
    hipLaunchKernelGGL(k4_mfma,      dim3(256),   dim3(512), 0, stream, st, ws);
    hipLaunchKernelGGL(k5_final,     dim3(64),    dim3(512), 0, stream, st, ws, out);
}